// Round 5
// baseline (455.224 us; speedup 1.0000x reference)
//
#include <hip/hip_runtime.h>
#include <math.h>

// GAT aggregator: embed-gather -> GAT layer1 -> GAT layer2 -> per-graph max pool.
// feat GEMM via bf16 MFMA with el/er folded in as extra output columns;
// per-edge softmax weights precomputed; layer-1 output bf16; graph-max fused
// into layer-2 gather. Gather edge-loop manually 4-wide pipelined for MLP.

#define HEADS 3
#define HD 64
#define FDIM (HEADS*HD)   // 192
#define NCOL 208          // 192 feat cols + 6 el/er cols + pad
#define NUM_GRAPHS 10
#define NPB 32            // nodes per feat block

typedef short bf16x8 __attribute__((ext_vector_type(8)));
typedef float f32x4  __attribute__((ext_vector_type(4)));

// ---------------- bf16 helpers ----------------
__device__ __forceinline__ float bf2f(unsigned short u) {
    return __uint_as_float(((unsigned int)u) << 16);
}
__device__ __forceinline__ unsigned short f2bf(float f) {
    unsigned int u = __float_as_uint(f);
    unsigned int r = (u + 0x7FFFu + ((u >> 16) & 1u)) >> 16;  // RNE
    return (unsigned short)r;
}

// ---------------- wave helpers ----------------
__device__ __forceinline__ int wave_incl_scan(int v, int lane) {
#pragma unroll
    for (int off = 1; off < 64; off <<= 1) {
        int t = __shfl_up(v, off);
        if (lane >= off) v += t;
    }
    return v;
}

__device__ __forceinline__ unsigned int fmap(float f) {
    unsigned int u = __float_as_uint(f);
    return (u & 0x80000000u) ? ~u : (u | 0x80000000u);
}
__device__ __forceinline__ float funmap(unsigned int u) {
    u = (u & 0x80000000u) ? (u & 0x7FFFFFFFu) : ~u;
    return __uint_as_float(u);
}

// ---------------- prep: Wt (bf16, transposed, +Wl/Wr cols), zero deg, init gm --
__global__ void k_prep(const float* __restrict__ W1, const float* __restrict__ al1,
                       const float* __restrict__ ar1,
                       const float* __restrict__ W2, const float* __restrict__ al2,
                       const float* __restrict__ ar2,
                       unsigned short* __restrict__ Wt1, unsigned short* __restrict__ Wt2,
                       int* __restrict__ deg, unsigned int* __restrict__ gm, int N) {
    int i = blockIdx.x * blockDim.x + threadIdx.x;
    if (i < 2 * NCOL * HD) {
        int l = i / (NCOL * HD), j = i % (NCOL * HD);
        int c = j >> 6, k = j & 63;
        const float* W  = l ? W2  : W1;
        const float* al = l ? al2 : al1;
        const float* ar = l ? ar2 : ar1;
        unsigned short* Wt = l ? Wt2 : Wt1;
        float v = 0.f;
        if (c < FDIM) {
            v = W[k * FDIM + c];
        } else if (c < FDIM + 6) {
            int h = c - FDIM;
            const float* a = (h < 3) ? al : ar;
            int hh = (h < 3) ? h : h - 3;
            float s = 0.f;
            for (int d = 0; d < HD; ++d)
                s += W[k * FDIM + hh * HD + d] * a[hh * HD + d];
            v = s;
        }
        Wt[j] = f2bf(v);
    }
    if (i < N) deg[i] = 0;
    if (i < NUM_GRAPHS * HD) gm[i] = 0x007FFFFFu; // fmap(-inf)
}

// ---------------- CSR build ----------------
__global__ void k_hist(const int* __restrict__ dst, int* __restrict__ deg, int E) {
    int i = blockIdx.x * blockDim.x + threadIdx.x;
    if (i < E) atomicAdd(&deg[dst[i]], 1);
}

__global__ void k_scan1(const int* __restrict__ deg, int* __restrict__ tmp,
                        int* __restrict__ partials, int N) {
    int t = threadIdx.x, b = blockIdx.x;
    int i = b * 256 + t;
    int v = (i < N) ? deg[i] : 0;
    int lane = t & 63, w = t >> 6;
    int incl = wave_incl_scan(v, lane);
    __shared__ int wsum[4];
    if (lane == 63) wsum[w] = incl;
    __syncthreads();
    int off = 0;
    for (int j = 0; j < w; ++j) off += wsum[j];
    incl += off;
    if (i < N) tmp[i] = incl;
    if (t == 255) partials[b] = incl;
}

__global__ void k_scan2(int* __restrict__ partials, int nb) {
    int t = threadIdx.x;                   // 512 threads, nb <= 512
    int v = (t < nb) ? partials[t] : 0;
    int lane = t & 63, w = t >> 6;
    int incl = wave_incl_scan(v, lane);
    __shared__ int wsum[8];
    if (lane == 63) wsum[w] = incl;
    __syncthreads();
    int off = 0;
    for (int j = 0; j < w; ++j) off += wsum[j];
    incl += off;
    if (t < nb) partials[t] = incl;
}

__global__ void k_scan3(const int* __restrict__ tmp, const int* __restrict__ deg,
                        const int* __restrict__ partials, int* __restrict__ rowptr,
                        int* __restrict__ cur1, int* __restrict__ cur2, int N) {
    int i = blockIdx.x * blockDim.x + threadIdx.x;
    if (i >= N) return;
    int b = i >> 8;
    int off = b ? partials[b - 1] : 0;
    int incl = tmp[i] + off;
    rowptr[i + 1] = incl;
    int start = incl - deg[i];
    cur1[i] = start;
    cur2[i] = start;
    if (i == 0) rowptr[0] = 0;
}

// ---------------- feat = x @ Wt via MFMA (el/er = extra cols) ----------------
__global__ __launch_bounds__(256) void k_feat_mfma(
        const unsigned short* __restrict__ xbf, const int* __restrict__ ids,
        const float* __restrict__ Wemb, const unsigned short* __restrict__ Wt,
        unsigned short* __restrict__ feat, float4* __restrict__ el4,
        float4* __restrict__ er4, int N) {
    __shared__ unsigned short xs[NPB][72];    // A tile (bf16), padded
    __shared__ unsigned short ls[NPB][200];   // C tile (bf16), padded
    int t = threadIdx.x;
    int lane = t & 63, w = t >> 6;
    int base = blockIdx.x * NPB;

    if (ids) {
        for (int i = t; i < NPB * 16; i += 256) {
            int row = i >> 4, c4 = (i & 15) * 4;
            int n = base + row;
            float4 v = {0.f, 0.f, 0.f, 0.f};
            if (n < N) v = *(const float4*)(Wemb + (size_t)ids[n] * HD + c4);
            unsigned short* dp = &xs[row][c4];
            dp[0] = f2bf(v.x); dp[1] = f2bf(v.y); dp[2] = f2bf(v.z); dp[3] = f2bf(v.w);
        }
    } else {
        for (int i = t; i < NPB * 16; i += 256) {
            int row = i >> 4, c4 = (i & 15) * 4;
            int n = base + row;
            ushort4 v = {0, 0, 0, 0};
            if (n < N) v = *(const ushort4*)(xbf + (size_t)n * HD + c4);
            *(ushort4*)(&xs[row][c4]) = v;
        }
    }

    int ntile = (w == 3) ? 4 : 3;
    bf16x8 bfrag[4][2];
#pragma unroll
    for (int c = 0; c < 4; ++c) {
        if (c >= ntile) break;
#pragma unroll
        for (int kk = 0; kk < 2; ++kk) {
            int coln = (w * 3 + c) * 16 + (lane & 15);
            int k0 = kk * 32 + (lane >> 4) * 8;
            bfrag[c][kk] = *(const bf16x8*)(Wt + (size_t)coln * HD + k0);
        }
    }
    __syncthreads();

    f32x4 acc[2][4];
#pragma unroll
    for (int r = 0; r < 2; ++r)
#pragma unroll
        for (int c = 0; c < 4; ++c) acc[r][c] = (f32x4){0.f, 0.f, 0.f, 0.f};
#pragma unroll
    for (int r = 0; r < 2; ++r)
#pragma unroll
        for (int kk = 0; kk < 2; ++kk) {
            int row = r * 16 + (lane & 15);
            int k0 = kk * 32 + (lane >> 4) * 8;
            bf16x8 a = *(const bf16x8*)(&xs[row][k0]);
#pragma unroll
            for (int c = 0; c < 4; ++c) {
                if (c >= ntile) break;
                acc[r][c] = __builtin_amdgcn_mfma_f32_16x16x32_bf16(a, bfrag[c][kk], acc[r][c], 0, 0, 0);
            }
        }

#pragma unroll
    for (int r = 0; r < 2; ++r)
#pragma unroll
        for (int c = 0; c < 3; ++c) {
            int col = (w * 3 + c) * 16 + (lane & 15);
#pragma unroll
            for (int j = 0; j < 4; ++j) {
                int row = r * 16 + (lane >> 4) * 4 + j;
                ls[row][col] = f2bf(acc[r][c][j]);
            }
        }

    if (w == 3) {
        int col = lane & 15;
        if (col < 6) {
#pragma unroll
            for (int r = 0; r < 2; ++r)
#pragma unroll
                for (int j = 0; j < 4; ++j) {
                    int row = r * 16 + (lane >> 4) * 4 + j;
                    int n = base + row;
                    if (n < N) {
                        float v = acc[r][3][j];
                        if (col < 3) ((float*)&el4[n])[col] = v;
                        else         ((float*)&er4[n])[col - 3] = v;
                    }
                }
        }
    }
    __syncthreads();

    for (int i = t; i < NPB * FDIM / 4; i += 256) {
        int idx = i * 4;
        int row = idx / FDIM, col = idx % FDIM;
        int n = base + row;
        if (n < N)
            *(ushort4*)(feat + (size_t)n * FDIM + col) = *(const ushort4*)(&ls[row][col]);
    }
}

// ---------------- per-edge weights + CSR scatter (fused) ----------------
__global__ void k_edgew_scatter(const int* __restrict__ src, const int* __restrict__ dst,
                                const float4* __restrict__ el4, const float4* __restrict__ er4,
                                int* __restrict__ cur, float4* __restrict__ ew, int E) {
    int i = blockIdx.x * blockDim.x + threadIdx.x;
    if (i >= E) return;
    int s = src[i], d = dst[i];
    float4 l = el4[s], r = er4[d];
    float e0 = l.x + r.x; e0 = e0 >= 0.f ? e0 : 0.2f * e0;
    float e1 = l.y + r.y; e1 = e1 >= 0.f ? e1 : 0.2f * e1;
    float e2 = l.z + r.z; e2 = e2 >= 0.f ? e2 : 0.2f * e2;
    int pos = atomicAdd(&cur[d], 1);
    float4 o;
    o.x = __int_as_float(s);
    o.y = __expf(e0); o.z = __expf(e1); o.w = __expf(e2);
    ew[pos] = o;
}

// ---------------- gather core: manually 4-wide pipelined edge loop -----------
struct GatherAcc { float a0, a1, a2, d0, d1, d2; };

__device__ __forceinline__ GatherAcc gather_edges(
        const float4* __restrict__ ew, const unsigned short* __restrict__ feat,
        int beg, int end, int lane) {
    float a0 = 0.f, a1 = 0.f, a2 = 0.f, d0 = 0.f, d1 = 0.f, d2 = 0.f;
    int j = beg;
    for (; j + 4 <= end; j += 4) {
        float4 e0 = ew[j + 0];
        float4 e1 = ew[j + 1];
        float4 e2 = ew[j + 2];
        float4 e3 = ew[j + 3];
        const unsigned short* f0 = feat + (size_t)__float_as_int(e0.x) * FDIM + lane;
        const unsigned short* f1 = feat + (size_t)__float_as_int(e1.x) * FDIM + lane;
        const unsigned short* f2 = feat + (size_t)__float_as_int(e2.x) * FDIM + lane;
        const unsigned short* f3 = feat + (size_t)__float_as_int(e3.x) * FDIM + lane;
        unsigned short v00 = f0[0], v01 = f0[64], v02 = f0[128];
        unsigned short v10 = f1[0], v11 = f1[64], v12 = f1[128];
        unsigned short v20 = f2[0], v21 = f2[64], v22 = f2[128];
        unsigned short v30 = f3[0], v31 = f3[64], v32 = f3[128];
        a0 = fmaf(e0.y, bf2f(v00), a0); d0 += e0.y;
        a1 = fmaf(e0.z, bf2f(v01), a1); d1 += e0.z;
        a2 = fmaf(e0.w, bf2f(v02), a2); d2 += e0.w;
        a0 = fmaf(e1.y, bf2f(v10), a0); d0 += e1.y;
        a1 = fmaf(e1.z, bf2f(v11), a1); d1 += e1.z;
        a2 = fmaf(e1.w, bf2f(v12), a2); d2 += e1.w;
        a0 = fmaf(e2.y, bf2f(v20), a0); d0 += e2.y;
        a1 = fmaf(e2.z, bf2f(v21), a1); d1 += e2.z;
        a2 = fmaf(e2.w, bf2f(v22), a2); d2 += e2.w;
        a0 = fmaf(e3.y, bf2f(v30), a0); d0 += e3.y;
        a1 = fmaf(e3.z, bf2f(v31), a1); d1 += e3.z;
        a2 = fmaf(e3.w, bf2f(v32), a2); d2 += e3.w;
    }
    for (; j < end; ++j) {
        float4 e = ew[j];
        const unsigned short* f = feat + (size_t)__float_as_int(e.x) * FDIM + lane;
        unsigned short v0 = f[0], v1 = f[64], v2 = f[128];
        a0 = fmaf(e.y, bf2f(v0), a0); d0 += e.y;
        a1 = fmaf(e.z, bf2f(v1), a1); d1 += e.z;
        a2 = fmaf(e.w, bf2f(v2), a2); d2 += e.w;
    }
    GatherAcc r = {a0, a1, a2, d0, d1, d2};
    return r;
}

// layer-1 gather: writes bf16
__global__ void k_gather1(const int* __restrict__ rowptr, const float4* __restrict__ ew,
                          const unsigned short* __restrict__ feat,
                          const float* __restrict__ b,
                          unsigned short* __restrict__ xout_bf, int N) {
    int wid = (blockIdx.x * blockDim.x + threadIdx.x) >> 6;
    int lane = threadIdx.x & 63;
    if (wid >= N) return;
    int beg = rowptr[wid], end = rowptr[wid + 1];
    GatherAcc g = gather_edges(ew, feat, beg, end, lane);
    float o = (g.a0 / fmaxf(g.d0, 1e-9f) + b[lane])
            + (g.a1 / fmaxf(g.d1, 1e-9f) + b[HD + lane])
            + (g.a2 / fmaxf(g.d2, 1e-9f) + b[2 * HD + lane]);
    xout_bf[(size_t)wid * HD + lane] = f2bf(o * (1.f / 3.f));
}

// layer-2 gather: fused per-graph max
__global__ void k_gather2(const int* __restrict__ rowptr, const float4* __restrict__ ew,
                          const unsigned short* __restrict__ feat,
                          const float* __restrict__ b,
                          const int* __restrict__ gid, unsigned int* __restrict__ gm,
                          int N) {
    __shared__ float sval[4][64];
    __shared__ int sgid[4];
    int wid = (blockIdx.x * blockDim.x + threadIdx.x) >> 6;
    int lane = threadIdx.x & 63, w = (threadIdx.x >> 6) & 3;
    bool valid = wid < N;
    float o = 0.f;
    int g = -1;
    if (valid) {
        int beg = rowptr[wid], end = rowptr[wid + 1];
        GatherAcc ga = gather_edges(ew, feat, beg, end, lane);
        o = (ga.a0 / fmaxf(ga.d0, 1e-9f) + b[lane])
          + (ga.a1 / fmaxf(ga.d1, 1e-9f) + b[HD + lane])
          + (ga.a2 / fmaxf(ga.d2, 1e-9f) + b[2 * HD + lane]);
        o *= (1.f / 3.f);
        g = gid[wid];
    }
    sval[w][lane] = o;
    if (lane == 0) sgid[w] = valid ? g : -1;
    __syncthreads();
    if (w == 0) {
        int gprev = -1; float m = 0.f;
#pragma unroll
        for (int q = 0; q < 4; ++q) {
            int gq = sgid[q];
            if (gq < 0) continue;
            if (gq == gprev) {
                m = fmaxf(m, sval[q][lane]);
            } else {
                if (gprev >= 0) atomicMax(&gm[gprev * HD + lane], fmap(m));
                gprev = gq; m = sval[q][lane];
            }
        }
        if (gprev >= 0) atomicMax(&gm[gprev * HD + lane], fmap(m));
    }
}

__global__ void k_gmax_final(const unsigned int* __restrict__ gm, float* __restrict__ out) {
    int i = blockIdx.x * blockDim.x + threadIdx.x;
    if (i < NUM_GRAPHS * HD) out[i] = funmap(gm[i]);
}

// ---------------- launch ----------------
extern "C" void kernel_launch(void* const* d_in, const int* in_sizes, int n_in,
                              void* d_out, int out_size, void* d_ws, size_t ws_size,
                              hipStream_t stream) {
    const int*   node_ids = (const int*)d_in[0];
    const int*   edge_src = (const int*)d_in[1];
    const int*   edge_dst = (const int*)d_in[2];
    const int*   gid      = (const int*)d_in[3];
    const float* Wemb     = (const float*)d_in[4];
    const float* W1  = (const float*)d_in[5];
    const float* al1 = (const float*)d_in[6];
    const float* ar1 = (const float*)d_in[7];
    const float* b1  = (const float*)d_in[8];
    const float* W2  = (const float*)d_in[9];
    const float* al2 = (const float*)d_in[10];
    const float* ar2 = (const float*)d_in[11];
    const float* b2  = (const float*)d_in[12];

    int N = in_sizes[0];
    int E = in_sizes[1];

    char* p = (char*)d_ws;
    auto alloc = [&](size_t bytes) {
        char* r = p;
        p += (bytes + 255) & ~(size_t)255;
        return (void*)r;
    };
    int*   deg      = (int*)alloc((size_t)N * 4);
    int*   tmp      = (int*)alloc((size_t)N * 4);
    int*   partials = (int*)alloc(512 * 4);
    int*   rowptr   = (int*)alloc((size_t)(N + 1) * 4);
    int*   cur1     = (int*)alloc((size_t)N * 4);
    int*   cur2     = (int*)alloc((size_t)N * 4);
    float4* ew      = (float4*)alloc((size_t)E * 16);
    unsigned short* feat = (unsigned short*)alloc((size_t)N * FDIM * 2);
    unsigned short* Wt1  = (unsigned short*)alloc((size_t)NCOL * HD * 2);
    unsigned short* Wt2  = (unsigned short*)alloc((size_t)NCOL * HD * 2);
    float4* el4     = (float4*)alloc((size_t)N * 16);
    float4* er4     = (float4*)alloc((size_t)N * 16);
    unsigned short* x1b = (unsigned short*)alloc((size_t)N * HD * 2);
    unsigned int* gm = (unsigned int*)alloc(NUM_GRAPHS * HD * 4);
    (void)ws_size;

    int nb = (N + 255) / 256;
    int prepN = (N > 2 * NCOL * HD) ? N : 2 * NCOL * HD;

    k_prep<<<dim3((prepN + 255) / 256), dim3(256), 0, stream>>>(
        W1, al1, ar1, W2, al2, ar2, Wt1, Wt2, deg, gm, N);
    k_hist<<<dim3((E + 255) / 256), dim3(256), 0, stream>>>(edge_dst, deg, E);
    k_scan1<<<dim3(nb), dim3(256), 0, stream>>>(deg, tmp, partials, N);
    k_scan2<<<dim3(1), dim3(512), 0, stream>>>(partials, nb);
    k_scan3<<<dim3(nb), dim3(256), 0, stream>>>(tmp, deg, partials, rowptr, cur1, cur2, N);

    dim3 featGrid((N + NPB - 1) / NPB), featBlk(256);
    dim3 aggGrid((N * 64 + 255) / 256), aggBlk(256);
    dim3 eGrid((E + 255) / 256), eBlk(256);

    // ---- layer 1 ----
    k_feat_mfma<<<featGrid, featBlk, 0, stream>>>(nullptr, node_ids, Wemb, Wt1,
                                                  feat, el4, er4, N);
    k_edgew_scatter<<<eGrid, eBlk, 0, stream>>>(edge_src, edge_dst, el4, er4, cur1, ew, E);
    k_gather1<<<aggGrid, aggBlk, 0, stream>>>(rowptr, ew, feat, b1, x1b, N);

    // ---- layer 2 ----
    k_feat_mfma<<<featGrid, featBlk, 0, stream>>>(x1b, nullptr, nullptr, Wt2,
                                                  feat, el4, er4, N);
    k_edgew_scatter<<<eGrid, eBlk, 0, stream>>>(edge_src, edge_dst, el4, er4, cur2, ew, E);
    k_gather2<<<aggGrid, aggBlk, 0, stream>>>(rowptr, ew, feat, b2, gid, gm, N);

    // ---- output ----
    k_gmax_final<<<dim3(1), dim3(NUM_GRAPHS * HD), 0, stream>>>(gm, (float*)d_out);
}

// Round 6
// 352.773 us; speedup vs baseline: 1.2904x; 1.2904x over previous
//
#include <hip/hip_runtime.h>
#include <math.h>

// GAT aggregator: embed-gather -> GAT layer1 -> GAT layer2 -> per-graph max pool.
// feat GEMM via bf16 MFMA with el/er folded in as extra output columns;
// per-edge softmax weights precomputed; x1 bf16; single plain gather kernel
// (R3-known-good body) used for both layers; separate small gmax kernels.

#define HEADS 3
#define HD 64
#define FDIM (HEADS*HD)   // 192
#define NCOL 208          // 192 feat cols + 6 el/er cols + pad
#define NUM_GRAPHS 10
#define NPB 32            // nodes per feat block

typedef short bf16x8 __attribute__((ext_vector_type(8)));
typedef float f32x4  __attribute__((ext_vector_type(4)));

// ---------------- bf16 helpers ----------------
__device__ __forceinline__ float bf2f(unsigned short u) {
    return __uint_as_float(((unsigned int)u) << 16);
}
__device__ __forceinline__ unsigned short f2bf(float f) {
    unsigned int u = __float_as_uint(f);
    unsigned int r = (u + 0x7FFFu + ((u >> 16) & 1u)) >> 16;  // RNE
    return (unsigned short)r;
}

// ---------------- wave helpers ----------------
__device__ __forceinline__ int wave_incl_scan(int v, int lane) {
#pragma unroll
    for (int off = 1; off < 64; off <<= 1) {
        int t = __shfl_up(v, off);
        if (lane >= off) v += t;
    }
    return v;
}

__device__ __forceinline__ unsigned int fmap(float f) {
    unsigned int u = __float_as_uint(f);
    return (u & 0x80000000u) ? ~u : (u | 0x80000000u);
}
__device__ __forceinline__ float funmap(unsigned int u) {
    u = (u & 0x80000000u) ? (u & 0x7FFFFFFFu) : ~u;
    return __uint_as_float(u);
}

// ---------------- prep: Wt (bf16, transposed, +Wl/Wr cols), zero deg, init gm --
__global__ void k_prep(const float* __restrict__ W1, const float* __restrict__ al1,
                       const float* __restrict__ ar1,
                       const float* __restrict__ W2, const float* __restrict__ al2,
                       const float* __restrict__ ar2,
                       unsigned short* __restrict__ Wt1, unsigned short* __restrict__ Wt2,
                       int* __restrict__ deg, unsigned int* __restrict__ gm, int N) {
    int i = blockIdx.x * blockDim.x + threadIdx.x;
    if (i < 2 * NCOL * HD) {
        int l = i / (NCOL * HD), j = i % (NCOL * HD);
        int c = j >> 6, k = j & 63;
        const float* W  = l ? W2  : W1;
        const float* al = l ? al2 : al1;
        const float* ar = l ? ar2 : ar1;
        unsigned short* Wt = l ? Wt2 : Wt1;
        float v = 0.f;
        if (c < FDIM) {
            v = W[k * FDIM + c];
        } else if (c < FDIM + 6) {
            int h = c - FDIM;
            const float* a = (h < 3) ? al : ar;
            int hh = (h < 3) ? h : h - 3;
            float s = 0.f;
            for (int d = 0; d < HD; ++d)
                s += W[k * FDIM + hh * HD + d] * a[hh * HD + d];
            v = s;
        }
        Wt[j] = f2bf(v);
    }
    if (i < N) deg[i] = 0;
    if (i < NUM_GRAPHS * HD) gm[i] = 0x007FFFFFu; // fmap(-inf)
}

// ---------------- CSR build ----------------
__global__ void k_hist(const int* __restrict__ dst, int* __restrict__ deg, int E) {
    int i = blockIdx.x * blockDim.x + threadIdx.x;
    if (i < E) atomicAdd(&deg[dst[i]], 1);
}

__global__ void k_scan1(const int* __restrict__ deg, int* __restrict__ tmp,
                        int* __restrict__ partials, int N) {
    int t = threadIdx.x, b = blockIdx.x;
    int i = b * 256 + t;
    int v = (i < N) ? deg[i] : 0;
    int lane = t & 63, w = t >> 6;
    int incl = wave_incl_scan(v, lane);
    __shared__ int wsum[4];
    if (lane == 63) wsum[w] = incl;
    __syncthreads();
    int off = 0;
    for (int j = 0; j < w; ++j) off += wsum[j];
    incl += off;
    if (i < N) tmp[i] = incl;
    if (t == 255) partials[b] = incl;
}

__global__ void k_scan2(int* __restrict__ partials, int nb) {
    int t = threadIdx.x;                   // 512 threads, nb <= 512
    int v = (t < nb) ? partials[t] : 0;
    int lane = t & 63, w = t >> 6;
    int incl = wave_incl_scan(v, lane);
    __shared__ int wsum[8];
    if (lane == 63) wsum[w] = incl;
    __syncthreads();
    int off = 0;
    for (int j = 0; j < w; ++j) off += wsum[j];
    incl += off;
    if (t < nb) partials[t] = incl;
}

__global__ void k_scan3(const int* __restrict__ tmp, const int* __restrict__ deg,
                        const int* __restrict__ partials, int* __restrict__ rowptr,
                        int* __restrict__ cur1, int* __restrict__ cur2, int N) {
    int i = blockIdx.x * blockDim.x + threadIdx.x;
    if (i >= N) return;
    int b = i >> 8;
    int off = b ? partials[b - 1] : 0;
    int incl = tmp[i] + off;
    rowptr[i + 1] = incl;
    int start = incl - deg[i];
    cur1[i] = start;
    cur2[i] = start;
    if (i == 0) rowptr[0] = 0;
}

// ---------------- feat = x @ Wt via MFMA (el/er = extra cols) ----------------
__global__ __launch_bounds__(256) void k_feat_mfma(
        const unsigned short* __restrict__ xbf, const int* __restrict__ ids,
        const float* __restrict__ Wemb, const unsigned short* __restrict__ Wt,
        unsigned short* __restrict__ feat, float4* __restrict__ el4,
        float4* __restrict__ er4, int N) {
    __shared__ unsigned short xs[NPB][72];    // A tile (bf16), padded
    __shared__ unsigned short ls[NPB][200];   // C tile (bf16), padded
    int t = threadIdx.x;
    int lane = t & 63, w = t >> 6;
    int base = blockIdx.x * NPB;

    if (ids) {
        for (int i = t; i < NPB * 16; i += 256) {
            int row = i >> 4, c4 = (i & 15) * 4;
            int n = base + row;
            float4 v = {0.f, 0.f, 0.f, 0.f};
            if (n < N) v = *(const float4*)(Wemb + (size_t)ids[n] * HD + c4);
            unsigned short* dp = &xs[row][c4];
            dp[0] = f2bf(v.x); dp[1] = f2bf(v.y); dp[2] = f2bf(v.z); dp[3] = f2bf(v.w);
        }
    } else {
        for (int i = t; i < NPB * 16; i += 256) {
            int row = i >> 4, c4 = (i & 15) * 4;
            int n = base + row;
            ushort4 v = {0, 0, 0, 0};
            if (n < N) v = *(const ushort4*)(xbf + (size_t)n * HD + c4);
            *(ushort4*)(&xs[row][c4]) = v;
        }
    }

    int ntile = (w == 3) ? 4 : 3;
    bf16x8 bfrag[4][2];
#pragma unroll
    for (int c = 0; c < 4; ++c) {
        if (c >= ntile) break;
#pragma unroll
        for (int kk = 0; kk < 2; ++kk) {
            int coln = (w * 3 + c) * 16 + (lane & 15);
            int k0 = kk * 32 + (lane >> 4) * 8;
            bfrag[c][kk] = *(const bf16x8*)(Wt + (size_t)coln * HD + k0);
        }
    }
    __syncthreads();

    f32x4 acc[2][4];
#pragma unroll
    for (int r = 0; r < 2; ++r)
#pragma unroll
        for (int c = 0; c < 4; ++c) acc[r][c] = (f32x4){0.f, 0.f, 0.f, 0.f};
#pragma unroll
    for (int r = 0; r < 2; ++r)
#pragma unroll
        for (int kk = 0; kk < 2; ++kk) {
            int row = r * 16 + (lane & 15);
            int k0 = kk * 32 + (lane >> 4) * 8;
            bf16x8 a = *(const bf16x8*)(&xs[row][k0]);
#pragma unroll
            for (int c = 0; c < 4; ++c) {
                if (c >= ntile) break;
                acc[r][c] = __builtin_amdgcn_mfma_f32_16x16x32_bf16(a, bfrag[c][kk], acc[r][c], 0, 0, 0);
            }
        }

#pragma unroll
    for (int r = 0; r < 2; ++r)
#pragma unroll
        for (int c = 0; c < 3; ++c) {
            int col = (w * 3 + c) * 16 + (lane & 15);
#pragma unroll
            for (int j = 0; j < 4; ++j) {
                int row = r * 16 + (lane >> 4) * 4 + j;
                ls[row][col] = f2bf(acc[r][c][j]);
            }
        }

    if (w == 3) {
        int col = lane & 15;
        if (col < 6) {
#pragma unroll
            for (int r = 0; r < 2; ++r)
#pragma unroll
                for (int j = 0; j < 4; ++j) {
                    int row = r * 16 + (lane >> 4) * 4 + j;
                    int n = base + row;
                    if (n < N) {
                        float v = acc[r][3][j];
                        if (col < 3) ((float*)&el4[n])[col] = v;
                        else         ((float*)&er4[n])[col - 3] = v;
                    }
                }
        }
    }
    __syncthreads();

    for (int i = t; i < NPB * FDIM / 4; i += 256) {
        int idx = i * 4;
        int row = idx / FDIM, col = idx % FDIM;
        int n = base + row;
        if (n < N)
            *(ushort4*)(feat + (size_t)n * FDIM + col) = *(const ushort4*)(&ls[row][col]);
    }
}

// ---------------- per-edge weights + CSR scatter (fused) ----------------
__global__ void k_edgew_scatter(const int* __restrict__ src, const int* __restrict__ dst,
                                const float4* __restrict__ el4, const float4* __restrict__ er4,
                                int* __restrict__ cur, float4* __restrict__ ew, int E) {
    int i = blockIdx.x * blockDim.x + threadIdx.x;
    if (i >= E) return;
    int s = src[i], d = dst[i];
    float4 l = el4[s], r = er4[d];
    float e0 = l.x + r.x; e0 = e0 >= 0.f ? e0 : 0.2f * e0;
    float e1 = l.y + r.y; e1 = e1 >= 0.f ? e1 : 0.2f * e1;
    float e2 = l.z + r.z; e2 = e2 >= 0.f ? e2 : 0.2f * e2;
    int pos = atomicAdd(&cur[d], 1);
    float4 o;
    o.x = __int_as_float(s);
    o.y = __expf(e0); o.z = __expf(e1); o.w = __expf(e2);
    ew[pos] = o;
}

// ---------------- gather aggregation + finalize (R3-known-good body) ---------
// one wave per node, lane = d. Single instantiation, used for both layers.
__global__ void k_gather(const int* __restrict__ rowptr, const float4* __restrict__ ew,
                         const unsigned short* __restrict__ feat,
                         const float* __restrict__ b,
                         unsigned short* __restrict__ xout, int N) {
    int wid = (blockIdx.x * blockDim.x + threadIdx.x) >> 6; // node
    int lane = threadIdx.x & 63;
    if (wid >= N) return;
    int beg = rowptr[wid], end = rowptr[wid + 1];
    float acc0 = 0.f, acc1 = 0.f, acc2 = 0.f;
    float ds0 = 0.f, ds1 = 0.f, ds2 = 0.f;
#pragma unroll 4
    for (int j = beg; j < end; ++j) {
        float4 e = ew[j];
        int s = __float_as_int(e.x);
        const unsigned short* frow = feat + (size_t)s * FDIM;
        acc0 = fmaf(e.y, bf2f(frow[lane]), acc0);
        acc1 = fmaf(e.z, bf2f(frow[HD + lane]), acc1);
        acc2 = fmaf(e.w, bf2f(frow[2 * HD + lane]), acc2);
        ds0 += e.y; ds1 += e.z; ds2 += e.w;
    }
    float o = (acc0 / fmaxf(ds0, 1e-9f) + b[lane])
            + (acc1 / fmaxf(ds1, 1e-9f) + b[HD + lane])
            + (acc2 / fmaxf(ds2, 1e-9f) + b[2 * HD + lane]);
    xout[(size_t)wid * HD + lane] = f2bf(o * (1.f / 3.f));
}

// ---------------- per-graph max pooling (bf16 input) ----------------
__global__ void k_gmax(const unsigned short* __restrict__ x, const int* __restrict__ gid,
                       unsigned int* __restrict__ gm, int N) {
    int lane = threadIdx.x; // 64 threads, lane = d
    int base = blockIdx.x * 64;
    int endn = min(base + 64, N);
    int cur = -1;
    float m = 0.f;
    for (int n = base; n < endn; ++n) {
        int g = gid[n];
        float v = bf2f(x[(size_t)n * HD + lane]);
        if (g != cur) {
            if (cur >= 0) atomicMax(&gm[cur * HD + lane], fmap(m));
            cur = g; m = v;
        } else {
            m = fmaxf(m, v);
        }
    }
    if (cur >= 0) atomicMax(&gm[cur * HD + lane], fmap(m));
}

__global__ void k_gmax_final(const unsigned int* __restrict__ gm, float* __restrict__ out) {
    int i = blockIdx.x * blockDim.x + threadIdx.x;
    if (i < NUM_GRAPHS * HD) out[i] = funmap(gm[i]);
}

// ---------------- launch ----------------
extern "C" void kernel_launch(void* const* d_in, const int* in_sizes, int n_in,
                              void* d_out, int out_size, void* d_ws, size_t ws_size,
                              hipStream_t stream) {
    const int*   node_ids = (const int*)d_in[0];
    const int*   edge_src = (const int*)d_in[1];
    const int*   edge_dst = (const int*)d_in[2];
    const int*   gid      = (const int*)d_in[3];
    const float* Wemb     = (const float*)d_in[4];
    const float* W1  = (const float*)d_in[5];
    const float* al1 = (const float*)d_in[6];
    const float* ar1 = (const float*)d_in[7];
    const float* b1  = (const float*)d_in[8];
    const float* W2  = (const float*)d_in[9];
    const float* al2 = (const float*)d_in[10];
    const float* ar2 = (const float*)d_in[11];
    const float* b2  = (const float*)d_in[12];

    int N = in_sizes[0];
    int E = in_sizes[1];

    char* p = (char*)d_ws;
    auto alloc = [&](size_t bytes) {
        char* r = p;
        p += (bytes + 255) & ~(size_t)255;
        return (void*)r;
    };
    int*   deg      = (int*)alloc((size_t)N * 4);
    int*   tmp      = (int*)alloc((size_t)N * 4);
    int*   partials = (int*)alloc(512 * 4);
    int*   rowptr   = (int*)alloc((size_t)(N + 1) * 4);
    int*   cur1     = (int*)alloc((size_t)N * 4);
    int*   cur2     = (int*)alloc((size_t)N * 4);
    float4* ew      = (float4*)alloc((size_t)E * 16);
    unsigned short* feat = (unsigned short*)alloc((size_t)N * FDIM * 2);
    unsigned short* Wt1  = (unsigned short*)alloc((size_t)NCOL * HD * 2);
    unsigned short* Wt2  = (unsigned short*)alloc((size_t)NCOL * HD * 2);
    float4* el4     = (float4*)alloc((size_t)N * 16);
    float4* er4     = (float4*)alloc((size_t)N * 16);
    unsigned short* x1b = (unsigned short*)alloc((size_t)N * HD * 2);
    unsigned int* gm = (unsigned int*)alloc(NUM_GRAPHS * HD * 4);
    (void)ws_size;

    int nb = (N + 255) / 256;
    int prepN = (N > 2 * NCOL * HD) ? N : 2 * NCOL * HD;

    k_prep<<<dim3((prepN + 255) / 256), dim3(256), 0, stream>>>(
        W1, al1, ar1, W2, al2, ar2, Wt1, Wt2, deg, gm, N);
    k_hist<<<dim3((E + 255) / 256), dim3(256), 0, stream>>>(edge_dst, deg, E);
    k_scan1<<<dim3(nb), dim3(256), 0, stream>>>(deg, tmp, partials, N);
    k_scan2<<<dim3(1), dim3(512), 0, stream>>>(partials, nb);
    k_scan3<<<dim3(nb), dim3(256), 0, stream>>>(tmp, deg, partials, rowptr, cur1, cur2, N);

    dim3 featGrid((N + NPB - 1) / NPB), featBlk(256);
    dim3 aggGrid((N * 64 + 255) / 256), aggBlk(256);
    dim3 eGrid((E + 255) / 256), eBlk(256);

    // ---- layer 1 ----
    k_feat_mfma<<<featGrid, featBlk, 0, stream>>>(nullptr, node_ids, Wemb, Wt1,
                                                  feat, el4, er4, N);
    k_edgew_scatter<<<eGrid, eBlk, 0, stream>>>(edge_src, edge_dst, el4, er4, cur1, ew, E);
    k_gather<<<aggGrid, aggBlk, 0, stream>>>(rowptr, ew, feat, b1, x1b, N);

    // ---- layer 2 ----
    k_feat_mfma<<<featGrid, featBlk, 0, stream>>>(x1b, nullptr, nullptr, Wt2,
                                                  feat, el4, er4, N);
    k_edgew_scatter<<<eGrid, eBlk, 0, stream>>>(edge_src, edge_dst, el4, er4, cur2, ew, E);
    k_gather<<<aggGrid, aggBlk, 0, stream>>>(rowptr, ew, feat, b2, x1b, N);

    // ---- per-graph max pooling ----
    k_gmax<<<dim3((N + 63) / 64), dim3(64), 0, stream>>>(x1b, gid, gm, N);
    k_gmax_final<<<dim3(1), dim3(NUM_GRAPHS * HD), 0, stream>>>(gm, (float*)d_out);
}